// Round 3
// baseline (62.977 us; speedup 1.0000x reference)
//
#include <hip/hip_runtime.h>
#include <math.h>

// Until_15753940041804: soft "until" operator.
// best[b,t,c] = log( sum_{k=0..63} 1/(S_k + exp(-s*psi[b,t+k,c])) ) / s
//   S_0 = exp(-s*1.0),  S_k = sum_{j<k} exp(-s*phi[b,t+j,c])  (k>=1).
// Pad past T: ep=0 (phi pad +1e4), eq=+INF (psi pad -1e4) -> rcp(inf)=0,
// reproducing the reference's padding + 'valid' mask exactly (R3-proven).
//
// R5 change vs R4 (failed, absmax 3.37): R4's 4-lane __shfl scan was the
// only unproven machinery; removed ALL cross-lane shuffles and reverted
// pair-rcp/finite-pad (back to R3-proven per-channel rcp + INF pad).
// Split-k is kept but remapped: o = lane (64 outputs/block), j = wave
// (8 k-groups of 8). Prefix S_{8j} handed off via LDS s_g + barrier;
// final 8-way reduction via LDS s_r + barrier.
//  * gather s_d[o + 8j + i]: consecutive lanes -> conflict-free ds_read_b128
//  * all branches (m<j, j==0, staging) wave-uniform -> no divergence
//  * wave 0 writes 64 consecutive float2 -> fully coalesced
//  * 16384 waves (8x R3), 8-step serial chains (vs 64), ~70 VGPR
//    -> 16+ waves/CU: latency-bound fix.

#define T_DIM   2048
#define W_WIN   64
#define OUT_T   64                      // outputs per block = lanes per wave
#define NW      8                       // waves per block = k-groups
#define NTHR    (OUT_T * NW)            // 512
#define STAGE   (OUT_T + W_WIN - 1)     // 127
#define KPL     (W_WIN / NW)            // 8 k's per (lane, wave)

__global__ __launch_bounds__(NTHR, 4) void until_kernel(
    const float* __restrict__ phi,
    const float* __restrict__ psi,
    const int*  __restrict__ scale_p,
    float* __restrict__ out)
{
    // s_d: x = ep ch0, y = ep ch1, z = eq ch0, w = eq ch1
    __shared__ float4 s_d[STAGE];
    __shared__ float2 s_g[OUT_T][NW];   // per-(output, wave) ep group sums
    __shared__ float2 s_r[OUT_T][NW];   // per-(output, wave) partial accs

    const int b   = blockIdx.y;
    const int t0  = blockIdx.x * OUT_T;
    const int tid = threadIdx.x;
    const int o   = tid & 63;           // output index within block
    const int j   = tid >> 6;           // k-group (wave) index
    const float s  = (float)(*scale_p);
    const float ns = -s;

    // Stage: exp once per element. Past T: ep=0, eq=+inf.
    if (tid < STAGE) {
        const int t = t0 + tid;
        float4 v;
        if (t < T_DIM) {
            const float2* __restrict__ phi2 = (const float2*)(phi + (size_t)b * T_DIM * 2);
            const float2* __restrict__ psi2 = (const float2*)(psi + (size_t)b * T_DIM * 2);
            float2 pv = phi2[t];
            float2 qv = psi2[t];
            v.x = __expf(ns * pv.x);
            v.y = __expf(ns * pv.y);
            v.z = __expf(ns * qv.x);
            v.w = __expf(ns * qv.y);
        } else {
            v.x = 0.f;      v.y = 0.f;
            v.z = INFINITY; v.w = INFINITY;
        }
        s_d[tid] = v;
    }
    __syncthreads();

    // This (lane, wave)'s 8 window elements: k = 8j + i. Consecutive lanes
    // read consecutive float4s -> conflict-free.
    const float4* __restrict__ sp = s_d + o + KPL * j;
    float4 v[KPL];
    #pragma unroll
    for (int i = 0; i < KPL; ++i) v[i] = sp[i];

    // Group sum of ep (both channels), publish for the prefix handoff.
    float g0 = 0.f, g1 = 0.f;
    #pragma unroll
    for (int i = 0; i < KPL; ++i) { g0 += v[i].x; g1 += v[i].y; }
    s_g[o][j] = make_float2(g0, g1);
    __syncthreads();

    // Exclusive prefix S_{8j} = sum of groups m < j (wave-uniform predicate).
    float sum0 = 0.f, sum1 = 0.f;
    #pragma unroll
    for (int m = 0; m < NW - 1; ++m) {
        const float2 gm = s_g[o][m];
        if (m < j) { sum0 += gm.x; sum1 += gm.y; }
    }

    const float Es = __expf(ns);        // k==0 term: min_phi forced to 1.0

    float accA0, accA1, accB0 = 0.f, accB1 = 0.f;

    // i = 0: global k==0 (j==0) uses base Es instead of S_0=0.
    {
        const float b0 = (j == 0) ? Es : sum0;
        const float b1 = (j == 0) ? Es : sum1;
        accA0 = __builtin_amdgcn_rcpf(b0 + v[0].z);
        accA1 = __builtin_amdgcn_rcpf(b1 + v[0].w);
        sum0 += v[0].x;
        sum1 += v[0].y;
    }
    #pragma unroll
    for (int i = 1; i < KPL; ++i) {
        const float r0 = __builtin_amdgcn_rcpf(sum0 + v[i].z);
        const float r1 = __builtin_amdgcn_rcpf(sum1 + v[i].w);
        if (i & 1) { accB0 += r0; accB1 += r1; }
        else       { accA0 += r0; accA1 += r1; }
        sum0 += v[i].x;
        sum1 += v[i].y;
    }

    // Publish partials; wave 0 reduces 8 groups and writes (coalesced).
    s_r[o][j] = make_float2(accA0 + accB0, accA1 + accB1);
    __syncthreads();

    if (j == 0) {
        float a0 = 0.f, a1 = 0.f;
        #pragma unroll
        for (int m = 0; m < NW; ++m) {
            const float2 rm = s_r[o][m];
            a0 += rm.x;
            a1 += rm.y;
        }
        float2* __restrict__ out2 = (float2*)(out + (size_t)b * T_DIM * 2);
        out2[t0 + o] = make_float2(__logf(a0) / s, __logf(a1) / s);
    }
}

extern "C" void kernel_launch(void* const* d_in, const int* in_sizes, int n_in,
                              void* d_out, int out_size, void* d_ws, size_t ws_size,
                              hipStream_t stream) {
    const float* phi   = (const float*)d_in[0];
    const float* psi   = (const float*)d_in[1];
    const int*   scale = (const int*)d_in[2];
    float* out = (float*)d_out;

    const int B = in_sizes[0] / (T_DIM * 2);   // 64
    dim3 grid(T_DIM / OUT_T, B);               // (32, 64) = 2048 blocks
    until_kernel<<<grid, dim3(NTHR), 0, stream>>>(phi, psi, scale, out);
}

// Round 4
// 60.131 us; speedup vs baseline: 1.0473x; 1.0473x over previous
//
#include <hip/hip_runtime.h>
#include <math.h>

// Until_15753940041804: soft "until" operator.
// best[b,t,c] = log( sum_{k=0..63} 1/(S_k + exp(-s*psi[b,t+k,c])) ) / s
//   S_0 = exp(-s*1.0),  S_k = sum_{j<k} exp(-s*phi[b,t+j,c])  (k>=1).
// Padding: past T we stage ep=0 (phi pad +1e4) and eq=+inf (psi pad -1e4),
// reproducing the reference's pad + 'valid' mask exactly (rcp(inf)=0).
//
// R6: REVERT to the R3 kernel (best harness-verified: 59.79us wall).
// Session evidence: three structurally different kernels (deep unroll /
// chunked dbuf / 8-wave split-k) all land at 61.4 +/- 1.6us wall. The
// timed region = harness poison-fill (268 MB @ ~6.6 TB/s = ~40.5us,
// at the HBM roofline) + ~15us harness-fixed overhead + this kernel
// (~3-6us, at its LDS/issue floor). R5's split-k (8x waves) regressed
// 3.2us from its extra barriers/LDS handoff; occupancy was NOT the
// bottleneck. This chunked single-pass structure is the measured best.
//
// Structure: 1 thread per output t (both channels), 256 thr/block.
// Stage exp once per element into LDS (319 float4/block), then an 8x8
// chunked, double-buffered k-loop: buf[8]+nxt[8] live (64 VGPRs), 8
// ds_read_b128 in flight per chunk, split accumulators to break the
// serial acc chain, per-channel v_rcp (2/iter), one __logf at the end.

#define T_DIM   2048
#define W_WIN   64
#define BLOCK_T 256
#define STAGE   (BLOCK_T + W_WIN - 1)   // 319
#define CH      8
#define NCHUNK  (W_WIN / CH)            // 8

__global__ __launch_bounds__(BLOCK_T) void until_kernel(
    const float* __restrict__ phi,
    const float* __restrict__ psi,
    const int*  __restrict__ scale_p,
    float* __restrict__ out)
{
    // x = ep ch0, y = ep ch1, z = eq ch0, w = eq ch1
    __shared__ float4 s_d[STAGE];

    const int b   = blockIdx.y;
    const int t0  = blockIdx.x * BLOCK_T;
    const int tid = threadIdx.x;
    const float s  = (float)(*scale_p);
    const float ns = -s;

    const float2* __restrict__ phi2 = (const float2*)(phi + (size_t)b * T_DIM * 2);
    const float2* __restrict__ psi2 = (const float2*)(psi + (size_t)b * T_DIM * 2);

    // Stage: exp once per element. Past T: ep=0, eq=+inf.
    for (int i = tid; i < STAGE; i += BLOCK_T) {
        int t = t0 + i;
        float4 v;
        if (t < T_DIM) {
            float2 pv = phi2[t];
            float2 qv = psi2[t];
            v.x = __expf(ns * pv.x);
            v.y = __expf(ns * pv.y);
            v.z = __expf(ns * qv.x);
            v.w = __expf(ns * qv.y);
        } else {
            v.x = 0.f; v.y = 0.f;
            v.z = INFINITY; v.w = INFINITY;
        }
        s_d[i] = v;
    }
    __syncthreads();

    const float Es = __expf(ns);   // k==0 term: min_phi forced to 1.0

    float accA0 = 0.f, accA1 = 0.f;   // even-k accumulators
    float accB0 = 0.f, accB1 = 0.f;   // odd-k accumulators
    float sum0  = 0.f, sum1  = 0.f;   // running S_k

    const float4* __restrict__ sp = s_d + tid;

    // Double-buffered 8x8 chunked loop over k = 0..63.
    float4 buf[CH];
    #pragma unroll
    for (int j = 0; j < CH; ++j) buf[j] = sp[j];

    #pragma unroll
    for (int c = 0; c < NCHUNK; ++c) {
        float4 nxt[CH];
        if (c + 1 < NCHUNK) {
            #pragma unroll
            for (int j = 0; j < CH; ++j) nxt[j] = sp[(c + 1) * CH + j];
        }
        #pragma unroll
        for (int j = 0; j < CH; ++j) {
            const float4 v = buf[j];
            const bool k0 = (c == 0) && (j == 0);       // compile-time
            const float b0 = k0 ? Es : sum0;
            const float b1 = k0 ? Es : sum1;
            const float r0 = __builtin_amdgcn_rcpf(b0 + v.z);
            const float r1 = __builtin_amdgcn_rcpf(b1 + v.w);
            if (j & 1) { accB0 += r0; accB1 += r1; }
            else       { accA0 += r0; accA1 += r1; }
            sum0 += v.x;
            sum1 += v.y;
        }
        if (c + 1 < NCHUNK) {
            #pragma unroll
            for (int j = 0; j < CH; ++j) buf[j] = nxt[j];
        }
    }

    const int t = t0 + tid;
    float2* __restrict__ out2 = (float2*)(out + (size_t)b * T_DIM * 2);
    out2[t] = make_float2(__logf(accA0 + accB0) / s, __logf(accA1 + accB1) / s);
}

extern "C" void kernel_launch(void* const* d_in, const int* in_sizes, int n_in,
                              void* d_out, int out_size, void* d_ws, size_t ws_size,
                              hipStream_t stream) {
    const float* phi   = (const float*)d_in[0];
    const float* psi   = (const float*)d_in[1];
    const int*   scale = (const int*)d_in[2];
    float* out = (float*)d_out;

    const int B = in_sizes[0] / (T_DIM * 2);   // 64
    dim3 grid(T_DIM / BLOCK_T, B);             // (8, 64) = 512 blocks
    until_kernel<<<grid, dim3(BLOCK_T), 0, stream>>>(phi, psi, scale, out);
}